// Round 6
// baseline (275.082 us; speedup 1.0000x reference)
//
#include <hip/hip_runtime.h>

// EdgeSoftmax: scores = exp(logits - segmax(logits, dst)); normalizer = segsum(scores, dst)
// logits: [E, 8] f32, dst: [E] i32 in [0,N); outputs: scores [E,8] f32 ++ normalizer [N,8] f32
//
// Measured facts (R1-R5, MI355X):
//  - global atomics are memory-side, ~19.8 G/s sink, regardless of scope/encoding
//  - scattered sub-line stores to a frontier > per-XCD L2 cost ~60B HBM each
//  - random 32B gathers from a 100MB array fetch each 64B line ~2x (R5 reduce: 200MB)
// Design: bucket sort (782 buckets of 128 nodes) CARRYING VALUES so all large streams
// are coalesced; reduce works entirely within its bucket's L2-hot 152KB value window;
// separate fully-coalesced score pass reading the 3.2MB L2-resident max table.

#define NPB_SHIFT 7
#define NPB 128               // nodes per bucket
#define NBMAX 1024            // max buckets in fast paths (N <= 131072)
#define CAP_V 4864            // value-path entries/bucket; lambda=4092, sigma=64 -> 12 sigma
#define CAP_B 5120            // id-path entries/bucket (R5 fallback)
#define EPB 8192              // edges per bin-pass block (256 thr x 32)
#define RCACHE 16             // per-lane register cache: covers node cnt <= 128

__global__ void esb_zero_kernel(int* __restrict__ bcursor, int nb) {
    int i = blockIdx.x * blockDim.x + threadIdx.x;
    if (i < nb) bcursor[i] = 0;
}

// ================= value-carrying fast path =================

__launch_bounds__(256)
__global__ void esbv_bin_kernel(const int* __restrict__ dst,
                                const float* __restrict__ logits,
                                int* __restrict__ bcursor,
                                unsigned char* __restrict__ eld,
                                float* __restrict__ eval,
                                int NB, int E) {
    __shared__ int hist[NBMAX];
    __shared__ int hbase[NBMAX];
    __shared__ int lcur[NBMAX];
    const int tid = threadIdx.x;
    const int base = blockIdx.x * EPB;

    for (int b = tid; b < NB; b += 256) hist[b] = 0;
    __syncthreads();

    // Phase A: LDS histogram of bucket counts for this tile.
#pragma unroll
    for (int i = 0; i < EPB / 256; ++i) {
        int e = base + i * 256 + tid;
        if (e < E) atomicAdd(&hist[dst[e] >> NPB_SHIFT], 1);
    }
    __syncthreads();

    // Phase B: one global atomic per (block, nonempty bucket) reserves a range.
    for (int b = tid; b < NB; b += 256) {
        int c = hist[b];
        hbase[b] = c ? atomicAdd(&bcursor[b], c) : 0;
        lcur[b] = 0;
    }
    __syncthreads();

    // Phase C: write local-node id (1B) + logit row (32B) into the bucket window.
    // Destination frontier ~NB active lines -> L2 write-combines.
#pragma unroll
    for (int i = 0; i < EPB / 256; ++i) {
        int e = base + i * 256 + tid;
        if (e < E) {
            int d = dst[e];  // L2-hot re-read
            int b = d >> NPB_SHIFT;
            int p = atomicAdd(&lcur[b], 1);
            int idx = hbase[b] + p;
            if (idx < CAP_V) {
                size_t g = (size_t)b * CAP_V + idx;
                eld[g] = (unsigned char)(d & (NPB - 1));
                const float4* lp = (const float4*)(logits + (size_t)e * 8);
                float4* vp = (float4*)(eval + g * 8);
                float4 v0 = lp[0];
                float4 v1 = lp[1];
                vp[0] = v0;
                vp[1] = v1;
            }
        }
    }
}

__launch_bounds__(512)
__global__ void esbv_reduce_kernel(const int* __restrict__ bcursor,
                                   const unsigned char* __restrict__ eld,
                                   const float* __restrict__ eval,
                                   float* __restrict__ maxtab,
                                   float* __restrict__ norm,
                                   int N) {
    __shared__ int counts[NPB];
    __shared__ int offs[NPB];
    __shared__ int lcur2[NPB];
    __shared__ unsigned short poslist[CAP_V];

    const int tid = threadIdx.x;
    const int b = blockIdx.x;
    const int node_base = b << NPB_SHIFT;
    const int nlocal = min(NPB, N - node_base);
    int cnt_b = bcursor[b];
    if (cnt_b > CAP_V) cnt_b = CAP_V;
    const unsigned char* ld_ = eld + (size_t)b * CAP_V;
    const float* ev = eval + (size_t)b * CAP_V * 8;

    if (tid < NPB) counts[tid] = 0;
    __syncthreads();

    // Phase 1: per-node counts (coalesced 1B stream).
    for (int i = tid; i < cnt_b; i += 512)
        atomicAdd(&counts[ld_[i]], 1);
    __syncthreads();

    // Phase 2: exclusive scan of 128 counts (wave 0, 2 per lane).
    if (tid < 64) {
        int l = tid;
        int a0 = counts[2 * l], a1 = counts[2 * l + 1];
        int s = a0 + a1;
        int pref = s;
        for (int off = 1; off < 64; off <<= 1) {
            int t = __shfl_up(pref, off, 64);
            if (l >= off) pref += t;
        }
        pref -= s;  // exclusive
        offs[2 * l] = pref;
        offs[2 * l + 1] = pref + a0;
        lcur2[2 * l] = 0;
        lcur2[2 * l + 1] = 0;
    }
    __syncthreads();

    // Phase 3: bin entry POSITIONS per node (u16, LDS).
    for (int i = tid; i < cnt_b; i += 512) {
        int l = ld_[i];
        int p = atomicAdd(&lcur2[l], 1);
        poslist[offs[l] + p] = (unsigned short)i;
    }
    __syncthreads();

    // Phase 4: wave per node; gather values from the bucket's L2-hot window.
    const int wave = tid >> 6;
    const int lane = tid & 63;
    const int h = lane & 7;
    const int g = lane >> 3;
    const float NINF = __int_as_float(0xFF800000);

    for (int ld = wave; ld < nlocal; ld += 8) {
        int node = node_base + ld;
        int cnt = counts[ld];
        int ib = offs[ld];
        float m = NINF;
        float acc = 0.0f;

        if (cnt <= 8 * RCACHE) {
            float vals[RCACHE];
#pragma unroll
            for (int i = 0; i < RCACHE; ++i) {
                if (i * 8 >= cnt) break;  // wave-uniform
                int j = g + i * 8;
                bool ok = j < cnt;
                int pos = ok ? (int)poslist[ib + j] : 0;
                float v = ok ? ev[(size_t)pos * 8 + h] : NINF;  // 8 lanes = 32B granule
                vals[i] = v;
                m = fmaxf(m, v);
            }
            m = fmaxf(m, __shfl_xor(m, 8, 64));
            m = fmaxf(m, __shfl_xor(m, 16, 64));
            m = fmaxf(m, __shfl_xor(m, 32, 64));
#pragma unroll
            for (int i = 0; i < RCACHE; ++i) {
                if (i * 8 >= cnt) break;  // wave-uniform
                if (g + i * 8 < cnt) acc += __expf(vals[i] - m);
            }
        } else {
            // rare fat node: streaming two-pass, L2-hot
            for (int j = g; j < cnt; j += 8)
                m = fmaxf(m, ev[(size_t)poslist[ib + j] * 8 + h]);
            m = fmaxf(m, __shfl_xor(m, 8, 64));
            m = fmaxf(m, __shfl_xor(m, 16, 64));
            m = fmaxf(m, __shfl_xor(m, 32, 64));
            for (int j = g; j < cnt; j += 8)
                acc += __expf(ev[(size_t)poslist[ib + j] * 8 + h] - m);
        }
        acc += __shfl_xor(acc, 8, 64);
        acc += __shfl_xor(acc, 16, 64);
        acc += __shfl_xor(acc, 32, 64);
        if (g == 0) norm[(size_t)node * 8 + h] = acc;    // 32B contiguous
        if (g == 1) maxtab[(size_t)node * 8 + h] = m;    // 32B contiguous
    }
}

// coalesced score pass (shared by both fast paths)
__launch_bounds__(256)
__global__ void esb_score_kernel(const float* __restrict__ logits,
                                 const int* __restrict__ dst,
                                 const float* __restrict__ maxtab,
                                 float* __restrict__ scores, int E) {
    int e = blockIdx.x * blockDim.x + threadIdx.x;
    if (e >= E) return;
    int d = dst[e];
    const float4* lp = (const float4*)(logits + (size_t)e * 8);
    float4 a = lp[0];
    float4 bb = lp[1];
    const float4* mp = (const float4*)(maxtab + (size_t)d * 8);  // 3.2MB table, L2-hot
    float4 m0 = mp[0];
    float4 m1 = mp[1];
    float4 s0, s1;
    s0.x = __expf(a.x - m0.x);
    s0.y = __expf(a.y - m0.y);
    s0.z = __expf(a.z - m0.z);
    s0.w = __expf(a.w - m0.w);
    s1.x = __expf(bb.x - m1.x);
    s1.y = __expf(bb.y - m1.y);
    s1.z = __expf(bb.z - m1.z);
    s1.w = __expf(bb.w - m1.w);
    float4* sp = (float4*)(scores + (size_t)e * 8);
    sp[0] = s0;
    sp[1] = s1;
}

// ================= R5 id-only path (fallback when ws too small for values) =================

__launch_bounds__(256)
__global__ void esb_bin_kernel(const int* __restrict__ dst,
                               int* __restrict__ bcursor,
                               unsigned int* __restrict__ entries,
                               int NB, int E) {
    __shared__ int hist[NBMAX];
    __shared__ int hbase[NBMAX];
    __shared__ int lcur[NBMAX];
    const int tid = threadIdx.x;
    const int base = blockIdx.x * EPB;

    for (int b = tid; b < NB; b += 256) hist[b] = 0;
    __syncthreads();
#pragma unroll
    for (int i = 0; i < EPB / 256; ++i) {
        int e = base + i * 256 + tid;
        if (e < E) atomicAdd(&hist[dst[e] >> NPB_SHIFT], 1);
    }
    __syncthreads();
    for (int b = tid; b < NB; b += 256) {
        int c = hist[b];
        hbase[b] = c ? atomicAdd(&bcursor[b], c) : 0;
        lcur[b] = 0;
    }
    __syncthreads();
#pragma unroll
    for (int i = 0; i < EPB / 256; ++i) {
        int e = base + i * 256 + tid;
        if (e < E) {
            int d = dst[e];
            int b = d >> NPB_SHIFT;
            int p = atomicAdd(&lcur[b], 1);
            int idx = hbase[b] + p;
            if (idx < CAP_B)
                entries[(size_t)b * CAP_B + idx] =
                    ((unsigned int)(d & (NPB - 1)) << 22) | (unsigned int)e;
        }
    }
}

__launch_bounds__(512)
__global__ void esb_reduce_kernel(const float* __restrict__ logits,
                                  const int* __restrict__ bcursor,
                                  const unsigned int* __restrict__ entries,
                                  float* __restrict__ maxtab,
                                  float* __restrict__ norm,
                                  int N, int E) {
    __shared__ int counts[NPB];
    __shared__ int offs[NPB];
    __shared__ int lcur2[NPB];
    __shared__ int idlist[CAP_B];

    const int tid = threadIdx.x;
    const int b = blockIdx.x;
    const int node_base = b << NPB_SHIFT;
    const int nlocal = min(NPB, N - node_base);
    int cnt_b = bcursor[b];
    if (cnt_b > CAP_B) cnt_b = CAP_B;
    const unsigned int* ent = entries + (size_t)b * CAP_B;

    if (tid < NPB) counts[tid] = 0;
    __syncthreads();
    for (int i = tid; i < cnt_b; i += 512)
        atomicAdd(&counts[ent[i] >> 22], 1);
    __syncthreads();
    if (tid < 64) {
        int l = tid;
        int a0 = counts[2 * l], a1 = counts[2 * l + 1];
        int s = a0 + a1;
        int pref = s;
        for (int off = 1; off < 64; off <<= 1) {
            int t = __shfl_up(pref, off, 64);
            if (l >= off) pref += t;
        }
        pref -= s;
        offs[2 * l] = pref;
        offs[2 * l + 1] = pref + a0;
        lcur2[2 * l] = 0;
        lcur2[2 * l + 1] = 0;
    }
    __syncthreads();
    for (int i = tid; i < cnt_b; i += 512) {
        unsigned int en = ent[i];
        int ld = en >> 22;
        int p = atomicAdd(&lcur2[ld], 1);
        idlist[offs[ld] + p] = (int)(en & 0x3FFFFFu);
    }
    __syncthreads();

    const int wave = tid >> 6;
    const int lane = tid & 63;
    const int h = lane & 7;
    const int g = lane >> 3;
    const float NINF = __int_as_float(0xFF800000);

    for (int ld = wave; ld < nlocal; ld += 8) {
        int node = node_base + ld;
        int cnt = counts[ld];
        int ib = offs[ld];
        float m = NINF;
        float acc = 0.0f;
        if (cnt <= 8 * RCACHE) {
            float vals[RCACHE];
#pragma unroll
            for (int i = 0; i < RCACHE; ++i) {
                if (i * 8 >= cnt) break;
                int j = g + i * 8;
                bool ok = j < cnt;
                int eid = ok ? idlist[ib + j] : 0;
                float v = ok ? logits[(size_t)eid * 8 + h] : NINF;
                vals[i] = v;
                m = fmaxf(m, v);
            }
            m = fmaxf(m, __shfl_xor(m, 8, 64));
            m = fmaxf(m, __shfl_xor(m, 16, 64));
            m = fmaxf(m, __shfl_xor(m, 32, 64));
#pragma unroll
            for (int i = 0; i < RCACHE; ++i) {
                if (i * 8 >= cnt) break;
                if (g + i * 8 < cnt) acc += __expf(vals[i] - m);
            }
        } else {
            for (int j = g; j < cnt; j += 8)
                m = fmaxf(m, logits[(size_t)idlist[ib + j] * 8 + h]);
            m = fmaxf(m, __shfl_xor(m, 8, 64));
            m = fmaxf(m, __shfl_xor(m, 16, 64));
            m = fmaxf(m, __shfl_xor(m, 32, 64));
            for (int j = g; j < cnt; j += 8)
                acc += __expf(logits[(size_t)idlist[ib + j] * 8 + h] - m);
        }
        acc += __shfl_xor(acc, 8, 64);
        acc += __shfl_xor(acc, 16, 64);
        acc += __shfl_xor(acc, 32, 64);
        if (g == 0) norm[(size_t)node * 8 + h] = acc;
        if (g == 1) maxtab[(size_t)node * 8 + h] = m;
    }
}

// ================= atomic fallback (any shape) =================

__device__ __forceinline__ void atomicMaxFloat(float* addr, float value) {
    if (value >= 0.0f)
        atomicMax((int*)addr, __float_as_int(value));
    else
        atomicMin((unsigned int*)addr, __float_as_uint(value));
}

__global__ void es_init_kernel(unsigned int* __restrict__ maxws,
                               float* __restrict__ norm, int nh) {
    int i = blockIdx.x * blockDim.x + threadIdx.x;
    if (i < nh) {
        maxws[i] = 0xFF800000u;
        norm[i] = 0.0f;
    }
}

__global__ void es_max_gen_kernel(const float* __restrict__ logits,
                                  const int* __restrict__ dst,
                                  float* __restrict__ maxws,
                                  int total, int H) {
    int i = blockIdx.x * blockDim.x + threadIdx.x;
    if (i >= total) return;
    int e = i / H;
    int h = i - e * H;
    atomicMaxFloat(maxws + (size_t)dst[e] * H + h, logits[i]);
}

__global__ void es_score_gen_kernel(const float* __restrict__ logits,
                                    const int* __restrict__ dst,
                                    const float* __restrict__ maxws,
                                    float* __restrict__ scores,
                                    float* __restrict__ norm,
                                    int total, int H) {
    int i = blockIdx.x * blockDim.x + threadIdx.x;
    if (i >= total) return;
    int e = i / H;
    int h = i - e * H;
    size_t idx = (size_t)dst[e] * H + h;
    float s = __expf(logits[i] - maxws[idx]);
    scores[i] = s;
    atomicAdd(norm + idx, s);
}

extern "C" void kernel_launch(void* const* d_in, const int* in_sizes, int n_in,
                              void* d_out, int out_size, void* d_ws, size_t ws_size,
                              hipStream_t stream) {
    const float* logits = (const float*)d_in[0];
    const int* dst = (const int*)d_in[1];
    const int EH = in_sizes[0];      // E*H
    const int E = in_sizes[1];       // edges
    const int H = EH / E;            // heads
    const int NH = out_size - EH;    // N*H

    float* scores = (float*)d_out;
    float* norm = (float*)d_out + (size_t)EH;

    const int threads = 256;
    const int N = (H > 0) ? NH / H : 0;
    const int NB = (N + NPB - 1) >> NPB_SHIFT;

    // value path ws: bcursor [NBMAX]i32 | eval [NB*CAP_V*8]f32 | eld [NB*CAP_V]u8 | maxtab [NH]f32
    const size_t need_v = (size_t)NBMAX * 4 + (size_t)NB * CAP_V * 32 +
                          (size_t)NB * CAP_V + (size_t)NH * 4;
    // id path ws: bcursor [NBMAX]i32 | entries [NB*CAP_B]u32 | maxtab [NH]f32
    const size_t need_i = (size_t)NBMAX * 4 + (size_t)NB * CAP_B * 4 + (size_t)NH * 4;

    if (H == 8 && N > 0 && NB <= NBMAX && ws_size >= need_v) {
        int* bcursor = (int*)d_ws;
        float* eval = (float*)((char*)d_ws + (size_t)NBMAX * 4);
        unsigned char* eld = (unsigned char*)(eval + (size_t)NB * CAP_V * 8);
        float* maxtab = (float*)(eld + (size_t)NB * CAP_V);

        hipLaunchKernelGGL(esb_zero_kernel,
                           dim3((NB + threads - 1) / threads), dim3(threads), 0, stream,
                           bcursor, NB);
        hipLaunchKernelGGL(esbv_bin_kernel,
                           dim3((E + EPB - 1) / EPB), dim3(threads), 0, stream,
                           dst, logits, bcursor, eld, eval, NB, E);
        hipLaunchKernelGGL(esbv_reduce_kernel,
                           dim3(NB), dim3(512), 0, stream,
                           bcursor, eld, eval, maxtab, norm, N);
        hipLaunchKernelGGL(esb_score_kernel,
                           dim3((E + threads - 1) / threads), dim3(threads), 0, stream,
                           logits, dst, maxtab, scores, E);
    } else if (H == 8 && N > 0 && NB <= NBMAX && E < (1 << 22) && ws_size >= need_i) {
        int* bcursor = (int*)d_ws;
        unsigned int* entries = (unsigned int*)d_ws + NBMAX;
        float* maxtab = (float*)((unsigned int*)d_ws + NBMAX + (size_t)NB * CAP_B);

        hipLaunchKernelGGL(esb_zero_kernel,
                           dim3((NB + threads - 1) / threads), dim3(threads), 0, stream,
                           bcursor, NB);
        hipLaunchKernelGGL(esb_bin_kernel,
                           dim3((E + EPB - 1) / EPB), dim3(threads), 0, stream,
                           dst, bcursor, entries, NB, E);
        hipLaunchKernelGGL(esb_reduce_kernel,
                           dim3(NB), dim3(512), 0, stream,
                           logits, bcursor, entries, maxtab, norm, N, E);
        hipLaunchKernelGGL(esb_score_kernel,
                           dim3((E + threads - 1) / threads), dim3(threads), 0, stream,
                           logits, dst, maxtab, scores, E);
    } else {
        float* maxws = (float*)d_ws;
        hipLaunchKernelGGL(es_init_kernel,
                           dim3((NH + threads - 1) / threads), dim3(threads), 0, stream,
                           (unsigned int*)maxws, norm, NH);
        int blocks = (EH + threads - 1) / threads;
        hipLaunchKernelGGL(es_max_gen_kernel, dim3(blocks), dim3(threads), 0, stream,
                           logits, dst, maxws, EH, H);
        hipLaunchKernelGGL(es_score_gen_kernel, dim3(blocks), dim3(threads), 0, stream,
                           logits, dst, maxws, scores, norm, EH, H);
    }
}

// Round 7
// 166.741 us; speedup vs baseline: 1.6498x; 1.6498x over previous
//
#include <hip/hip_runtime.h>

// EdgeSoftmax: scores = exp(logits - segmax(logits, dst)); normalizer = segsum(scores, dst)
// logits: [E, 8] f32, dst: [E] i32 in [0,N); outputs: scores [E,8] f32 ++ normalizer [N,8] f32
//
// Measured facts (R1-R6, MI355X):
//  - global atomics: memory-side, ~19.8 G/s sink, regardless of scope/encoding
//  - scattered sub-line stores: ~60B HBM each once write frontier > per-XCD L2;
//    carrying 32B payloads through a scatter is 6x worse than 4B ids (R6 regression)
//  - random 32B gathers from 100MB: each 64B line fetched ~2x (structural)
// Design (R5 structure + streaming reduce):
//  1) esb_bin: bucket sort of edge IDS only (782 buckets x 128 nodes), LDS histogram,
//     one global atomic per (block,bucket), 4B scattered id writes (small frontier).
//  2) eso_reduce: one block per bucket; stream entries coalesced, gather logits 32B,
//     online-softmax update of per-(node,head) (max,sum) packed u64 in LDS via CAS.
//     Single pass, no binning, max MLP.
//  3) esb_score: fully coalesced per-edge pass reading the L2-resident max table.

#define NPB_SHIFT 7
#define NPB 128               // nodes per bucket
#define NBMAX 1024            // max buckets in fast path (N <= 131072)
#define CAP_B 5120            // entries/bucket; lambda=4096, sigma=64 -> 16 sigma
#define EPB 8192              // edges per bin-pass block (256 thr x 32)

__global__ void esb_zero_kernel(int* __restrict__ bcursor, int nb) {
    int i = blockIdx.x * blockDim.x + threadIdx.x;
    if (i < nb) bcursor[i] = 0;
}

// ---------------- pass 1: bin edge ids into buckets ----------------
__launch_bounds__(256)
__global__ void esb_bin_kernel(const int* __restrict__ dst,
                               int* __restrict__ bcursor,
                               unsigned int* __restrict__ entries,
                               int NB, int E) {
    __shared__ int hist[NBMAX];
    __shared__ int hbase[NBMAX];
    __shared__ int lcur[NBMAX];
    const int tid = threadIdx.x;
    const int base = blockIdx.x * EPB;

    for (int b = tid; b < NB; b += 256) hist[b] = 0;
    __syncthreads();
#pragma unroll
    for (int i = 0; i < EPB / 256; ++i) {
        int e = base + i * 256 + tid;
        if (e < E) atomicAdd(&hist[dst[e] >> NPB_SHIFT], 1);
    }
    __syncthreads();
    for (int b = tid; b < NB; b += 256) {
        int c = hist[b];
        hbase[b] = c ? atomicAdd(&bcursor[b], c) : 0;
        lcur[b] = 0;
    }
    __syncthreads();
#pragma unroll
    for (int i = 0; i < EPB / 256; ++i) {
        int e = base + i * 256 + tid;
        if (e < E) {
            int d = dst[e];  // L2-hot re-read
            int b = d >> NPB_SHIFT;
            int p = atomicAdd(&lcur[b], 1);
            int idx = hbase[b] + p;
            if (idx < CAP_B)
                entries[(size_t)b * CAP_B + idx] =
                    ((unsigned int)(d & (NPB - 1)) << 22) | (unsigned int)e;
        }
    }
}

// ---------------- pass 2: streaming online-softmax reduce ----------------
// One block per bucket. 8 lanes per entry (h = tid&7) -> 32B coalesced gather.
// Per-(node,head) state: u64 { lo: max bits, hi: sum bits } in LDS, CAS-updated.
__launch_bounds__(512)
__global__ void eso_reduce_kernel(const float* __restrict__ logits,
                                  const int* __restrict__ bcursor,
                                  const unsigned int* __restrict__ entries,
                                  float* __restrict__ maxtab,
                                  float* __restrict__ norm,
                                  int N) {
    __shared__ unsigned long long state[NPB * 8];  // 8 KB

    const int tid = threadIdx.x;
    const int b = blockIdx.x;
    const int node_base = b << NPB_SHIFT;
    const int nlocal = min(NPB, N - node_base);
    int cnt_b = bcursor[b];
    if (cnt_b > CAP_B) cnt_b = CAP_B;
    const unsigned int* ent = entries + (size_t)b * CAP_B;

    const unsigned long long INIT = 0xFF800000ull;  // m = -inf, s = 0.0f
    for (int i = tid; i < NPB * 8; i += 512) state[i] = INIT;
    __syncthreads();

    const int h = tid & 7;
    for (int p = (tid >> 3); p < cnt_b; p += 64) {
        unsigned int en = ent[p];                 // 8 lanes broadcast
        int ld = (int)(en >> 22);
        int eid = (int)(en & 0x3FFFFFu);
        float v = logits[(size_t)eid * 8 + h];    // 32B granule per entry
        unsigned long long* cell = &state[(ld << 3) + h];
        unsigned long long old = *cell;           // plain read; CAS verifies
        while (true) {
            float m = __uint_as_float((unsigned int)(old & 0xFFFFFFFFull));
            float s = __uint_as_float((unsigned int)(old >> 32));
            float nm, ns;
            if (v <= m) {                         // includes first-touch? no: m=-inf < v
                nm = m;
                ns = s + __expf(v - m);
            } else {                              // new max (also first touch)
                nm = v;
                ns = s * __expf(m - v) + 1.0f;    // m=-inf: exp=0 -> ns=1
            }
            unsigned long long nw =
                ((unsigned long long)__float_as_uint(ns) << 32) |
                (unsigned long long)__float_as_uint(nm);
            unsigned long long prev = atomicCAS(cell, old, nw);
            if (prev == old) break;
            old = prev;
        }
    }
    __syncthreads();

    // coalesced write-out of max table and normalizer
    for (int i = tid; i < nlocal * 8; i += 512) {
        unsigned long long st = state[i];
        maxtab[((size_t)node_base << 3) + i] =
            __uint_as_float((unsigned int)(st & 0xFFFFFFFFull));
        norm[((size_t)node_base << 3) + i] =
            __uint_as_float((unsigned int)(st >> 32));
    }
}

// ---------------- pass 3: coalesced score pass ----------------
__launch_bounds__(256)
__global__ void esb_score_kernel(const float* __restrict__ logits,
                                 const int* __restrict__ dst,
                                 const float* __restrict__ maxtab,
                                 float* __restrict__ scores, int E) {
    int e = blockIdx.x * blockDim.x + threadIdx.x;
    if (e >= E) return;
    int d = dst[e];
    const float4* lp = (const float4*)(logits + (size_t)e * 8);
    float4 a = lp[0];
    float4 bb = lp[1];
    const float4* mp = (const float4*)(maxtab + (size_t)d * 8);  // 3.2MB, L2-hot
    float4 m0 = mp[0];
    float4 m1 = mp[1];
    float4 s0, s1;
    s0.x = __expf(a.x - m0.x);
    s0.y = __expf(a.y - m0.y);
    s0.z = __expf(a.z - m0.z);
    s0.w = __expf(a.w - m0.w);
    s1.x = __expf(bb.x - m1.x);
    s1.y = __expf(bb.y - m1.y);
    s1.z = __expf(bb.z - m1.z);
    s1.w = __expf(bb.w - m1.w);
    float4* sp = (float4*)(scores + (size_t)e * 8);
    sp[0] = s0;
    sp[1] = s1;
}

// ---------------- fallback path (device-scope atomics, any shape) ----------------

__device__ __forceinline__ void atomicMaxFloat(float* addr, float value) {
    if (value >= 0.0f)
        atomicMax((int*)addr, __float_as_int(value));
    else
        atomicMin((unsigned int*)addr, __float_as_uint(value));
}

__global__ void es_init_kernel(unsigned int* __restrict__ maxws,
                               float* __restrict__ norm, int nh) {
    int i = blockIdx.x * blockDim.x + threadIdx.x;
    if (i < nh) {
        maxws[i] = 0xFF800000u;
        norm[i] = 0.0f;
    }
}

__global__ void es_max_gen_kernel(const float* __restrict__ logits,
                                  const int* __restrict__ dst,
                                  float* __restrict__ maxws,
                                  int total, int H) {
    int i = blockIdx.x * blockDim.x + threadIdx.x;
    if (i >= total) return;
    int e = i / H;
    int h = i - e * H;
    atomicMaxFloat(maxws + (size_t)dst[e] * H + h, logits[i]);
}

__global__ void es_score_gen_kernel(const float* __restrict__ logits,
                                    const int* __restrict__ dst,
                                    const float* __restrict__ maxws,
                                    float* __restrict__ scores,
                                    float* __restrict__ norm,
                                    int total, int H) {
    int i = blockIdx.x * blockDim.x + threadIdx.x;
    if (i >= total) return;
    int e = i / H;
    int h = i - e * H;
    size_t idx = (size_t)dst[e] * H + h;
    float s = __expf(logits[i] - maxws[idx]);
    scores[i] = s;
    atomicAdd(norm + idx, s);
}

extern "C" void kernel_launch(void* const* d_in, const int* in_sizes, int n_in,
                              void* d_out, int out_size, void* d_ws, size_t ws_size,
                              hipStream_t stream) {
    const float* logits = (const float*)d_in[0];
    const int* dst = (const int*)d_in[1];
    const int EH = in_sizes[0];      // E*H
    const int E = in_sizes[1];       // edges
    const int H = EH / E;            // heads
    const int NH = out_size - EH;    // N*H

    float* scores = (float*)d_out;
    float* norm = (float*)d_out + (size_t)EH;

    const int threads = 256;
    const int N = (H > 0) ? NH / H : 0;
    const int NB = (N + NPB - 1) >> NPB_SHIFT;

    // ws layout: bcursor [NBMAX]i32 | entries [NB*CAP_B]u32 | maxtab [NH]f32
    const size_t need = (size_t)NBMAX * 4 + (size_t)NB * CAP_B * 4 + (size_t)NH * 4;

    if (H == 8 && N > 0 && NB <= NBMAX && E < (1 << 22) && ws_size >= need) {
        int* bcursor = (int*)d_ws;
        unsigned int* entries = (unsigned int*)d_ws + NBMAX;
        float* maxtab = (float*)((unsigned int*)d_ws + NBMAX + (size_t)NB * CAP_B);

        hipLaunchKernelGGL(esb_zero_kernel,
                           dim3((NB + threads - 1) / threads), dim3(threads), 0, stream,
                           bcursor, NB);
        hipLaunchKernelGGL(esb_bin_kernel,
                           dim3((E + EPB - 1) / EPB), dim3(threads), 0, stream,
                           dst, bcursor, entries, NB, E);
        hipLaunchKernelGGL(eso_reduce_kernel,
                           dim3(NB), dim3(512), 0, stream,
                           logits, bcursor, entries, maxtab, norm, N);
        hipLaunchKernelGGL(esb_score_kernel,
                           dim3((E + threads - 1) / threads), dim3(threads), 0, stream,
                           logits, dst, maxtab, scores, E);
    } else {
        float* maxws = (float*)d_ws;
        hipLaunchKernelGGL(es_init_kernel,
                           dim3((NH + threads - 1) / threads), dim3(threads), 0, stream,
                           (unsigned int*)maxws, norm, NH);
        int blocks = (EH + threads - 1) / threads;
        hipLaunchKernelGGL(es_max_gen_kernel, dim3(blocks), dim3(threads), 0, stream,
                           logits, dst, maxws, EH, H);
        hipLaunchKernelGGL(es_score_gen_kernel, dim3(blocks), dim3(threads), 0, stream,
                           logits, dst, maxws, scores, norm, EH, H);
    }
}